// Round 1
// baseline (1850.631 us; speedup 1.0000x reference)
//
#include <hip/hip_runtime.h>
#include <math.h>

#define T_LEN 20000
#define HID 150
#define BN 160
#define MAXN 10

// ---------------------------------------------------------------------------
// Generic fp32 GEMM: C[M,150] = act(A[M,K] @ B[K,150] (+ bias))
// BM=32 rows/block, full N=150 (padded to 160 in LDS), BK=32.
// 256 threads: thread (tr,tc) computes rows {2tr,2tr+1} x cols {10tc..10tc+9}.
// M assumed divisible by 32 (M=20000 -> 625 blocks).
// ---------------------------------------------------------------------------
__global__ __launch_bounds__(256) void gemm150(
    const float* __restrict__ A, const float* __restrict__ B,
    const float* __restrict__ bias, float* __restrict__ C,
    int K, int relu_flag)
{
    __shared__ float As[32][33];
    __shared__ float Bs[32][BN];
    const int tid = threadIdx.x;
    const int m0 = blockIdx.x * 32;
    const int tr = tid >> 4;
    const int tc = tid & 15;

    float acc[2][10];
    #pragma unroll
    for (int r = 0; r < 2; ++r)
        #pragma unroll
        for (int q = 0; q < 10; ++q) acc[r][q] = 0.f;

    for (int k0 = 0; k0 < K; k0 += 32) {
        for (int t = tid; t < 32 * 32; t += 256) {
            int r = t >> 5, kk = t & 31;
            int gk = k0 + kk;
            As[r][kk] = (gk < K) ? A[(long)(m0 + r) * K + gk] : 0.f;
        }
        for (int t = tid; t < 32 * BN; t += 256) {
            int kk = t / BN, e = t - kk * BN;
            int gk = k0 + kk;
            Bs[kk][e] = (gk < K && e < HID) ? B[(long)gk * HID + e] : 0.f;
        }
        __syncthreads();
        #pragma unroll
        for (int kk = 0; kk < 32; ++kk) {
            float a0 = As[2 * tr][kk];
            float a1 = As[2 * tr + 1][kk];
            float bv[10];
            #pragma unroll
            for (int q = 0; q < 10; ++q) bv[q] = Bs[kk][tc * 10 + q];
            #pragma unroll
            for (int q = 0; q < 10; ++q) {
                acc[0][q] += a0 * bv[q];
                acc[1][q] += a1 * bv[q];
            }
        }
        __syncthreads();
    }

    #pragma unroll
    for (int r = 0; r < 2; ++r) {
        int gm = m0 + 2 * tr + r;
        #pragma unroll
        for (int q = 0; q < 10; ++q) {
            int e = tc * 10 + q;
            if (e < HID) {
                float v = acc[r][q];
                if (bias) v += bias[e];
                if (relu_flag) v = fmaxf(v, 0.f);
                C[(long)gm * HID + e] = v;
            }
        }
    }
}

// ---------------------------------------------------------------------------
// Attention tail: logits[m] = relu(X1[m,:]@W2 + b2) @ W3 + b3
// Same GEMM core (K=150) with a dot-product epilogue. 32 rows/block.
// ---------------------------------------------------------------------------
__global__ __launch_bounds__(256) void attn_tail(
    const float* __restrict__ X1, const float* __restrict__ W2,
    const float* __restrict__ b2, const float* __restrict__ W3,
    const float* __restrict__ b3, float* __restrict__ logits)
{
    __shared__ float As[32][33];
    __shared__ float Bs[32][BN];
    __shared__ float red[32][16];
    const int tid = threadIdx.x;
    const int m0 = blockIdx.x * 32;
    const int tr = tid >> 4;
    const int tc = tid & 15;
    const int K = HID;

    float acc[2][10];
    #pragma unroll
    for (int r = 0; r < 2; ++r)
        #pragma unroll
        for (int q = 0; q < 10; ++q) acc[r][q] = 0.f;

    for (int k0 = 0; k0 < K; k0 += 32) {
        for (int t = tid; t < 32 * 32; t += 256) {
            int r = t >> 5, kk = t & 31;
            int gk = k0 + kk;
            As[r][kk] = (gk < K) ? X1[(long)(m0 + r) * K + gk] : 0.f;
        }
        for (int t = tid; t < 32 * BN; t += 256) {
            int kk = t / BN, e = t - kk * BN;
            int gk = k0 + kk;
            Bs[kk][e] = (gk < K && e < HID) ? W2[(long)gk * HID + e] : 0.f;
        }
        __syncthreads();
        #pragma unroll
        for (int kk = 0; kk < 32; ++kk) {
            float a0 = As[2 * tr][kk];
            float a1 = As[2 * tr + 1][kk];
            float bv[10];
            #pragma unroll
            for (int q = 0; q < 10; ++q) bv[q] = Bs[kk][tc * 10 + q];
            #pragma unroll
            for (int q = 0; q < 10; ++q) {
                acc[0][q] += a0 * bv[q];
                acc[1][q] += a1 * bv[q];
            }
        }
        __syncthreads();
    }

    float partial[2] = {0.f, 0.f};
    #pragma unroll
    for (int r = 0; r < 2; ++r)
        #pragma unroll
        for (int q = 0; q < 10; ++q) {
            int e = tc * 10 + q;
            if (e < HID) {
                float v = fmaxf(acc[r][q] + b2[e], 0.f);
                partial[r] += v * W3[e];
            }
        }
    #pragma unroll
    for (int r = 0; r < 2; ++r) red[2 * tr + r][tc] = partial[r];
    __syncthreads();
    if (tid < 32) {
        float s = b3[0];
        #pragma unroll
        for (int t = 0; t < 16; ++t) s += red[tid][t];
        logits[m0 + tid] = s;
    }
}

// ---------------------------------------------------------------------------
// Span kernel for one width n: 64 spans per block.
// Phase 0: per-span softmax over window logits (+ stage b2/W3 in LDS).
// Phase 1: h1[i][d] = relu(U[s]+V[s+n-1]+sum_j w_j P[s+j])  (sc_b1 folded in U)
// Phase 2: block GEMM h2 = h1 @ sc_W2 (W2 staged in 25-row LDS chunks)
// Phase 3: score = relu(h2+b2) . W3 + b3, cross-thread LDS reduce.
// ---------------------------------------------------------------------------
__global__ __launch_bounds__(256) void span_score(
    const float* __restrict__ U, const float* __restrict__ V,
    const float* __restrict__ P, const float* __restrict__ logits,
    const float* __restrict__ W2, const float* __restrict__ b2,
    const float* __restrict__ W3, const float* __restrict__ b3,
    float* __restrict__ out, int n, int S, int out_off)
{
    __shared__ float h1[64][151];
    __shared__ float W2c[25 * HID];
    __shared__ float wbuf[64][MAXN];
    __shared__ float b2s[HID];
    __shared__ float W3s[HID];
    __shared__ float red[64][16];

    const int tid = threadIdx.x;
    const int s0 = blockIdx.x * 64;

    for (int t = tid; t < HID; t += 256) { b2s[t] = b2[t]; W3s[t] = W3[t]; }

    if (tid < 64) {
        int s = s0 + tid; if (s > S - 1) s = S - 1;
        float lg[MAXN];
        float mx = -1e30f;
        for (int j = 0; j < n; ++j) { lg[j] = logits[s + j]; mx = fmaxf(mx, lg[j]); }
        float sum = 0.f;
        for (int j = 0; j < n; ++j) { lg[j] = expf(lg[j] - mx); sum += lg[j]; }
        float inv = 1.f / sum;
        for (int j = 0; j < n; ++j) wbuf[tid][j] = lg[j] * inv;
    }
    __syncthreads();

    for (int idx = tid; idx < 64 * HID; idx += 256) {
        int i = idx / HID;
        int d = idx - i * HID;
        int s = s0 + i; if (s > S - 1) s = S - 1;
        float pre = U[(long)s * HID + d] + V[(long)(s + n - 1) * HID + d];
        for (int j = 0; j < n; ++j) pre += wbuf[i][j] * P[(long)(s + j) * HID + d];
        h1[i][d] = fmaxf(pre, 0.f);
    }
    __syncthreads();

    const int tr = tid >> 4;   // span group: spans 4tr..4tr+3
    const int tc = tid & 15;   // col group: cols 10tc..10tc+9 (tc<15 active)
    float acc[4][10];
    #pragma unroll
    for (int r = 0; r < 4; ++r)
        #pragma unroll
        for (int q = 0; q < 10; ++q) acc[r][q] = 0.f;

    for (int d0 = 0; d0 < HID; d0 += 25) {
        for (int t = tid; t < 25 * HID; t += 256) W2c[t] = W2[(long)d0 * HID + t];
        __syncthreads();
        if (tc < 15) {
            #pragma unroll
            for (int dd = 0; dd < 25; ++dd) {
                float a[4];
                #pragma unroll
                for (int r = 0; r < 4; ++r) a[r] = h1[4 * tr + r][d0 + dd];
                float bv[10];
                #pragma unroll
                for (int q = 0; q < 10; ++q) bv[q] = W2c[dd * HID + tc * 10 + q];
                #pragma unroll
                for (int r = 0; r < 4; ++r)
                    #pragma unroll
                    for (int q = 0; q < 10; ++q) acc[r][q] += a[r] * bv[q];
            }
        }
        __syncthreads();
    }

    float partial[4] = {0.f, 0.f, 0.f, 0.f};
    if (tc < 15) {
        #pragma unroll
        for (int r = 0; r < 4; ++r)
            #pragma unroll
            for (int q = 0; q < 10; ++q) {
                int e = tc * 10 + q;
                float h2 = fmaxf(acc[r][q] + b2s[e], 0.f);
                partial[r] += h2 * W3s[e];
            }
    }
    #pragma unroll
    for (int r = 0; r < 4; ++r) red[4 * tr + r][tc] = partial[r];
    __syncthreads();
    if (tid < 64) {
        int s = s0 + tid;
        if (s < S) {
            float sc = b3[0];
            #pragma unroll
            for (int t = 0; t < 16; ++t) sc += red[tid][t];
            out[out_off + s] = sc;
        }
    }
}

// ---------------------------------------------------------------------------
extern "C" void kernel_launch(void* const* d_in, const int* in_sizes, int n_in,
                              void* d_out, int out_size, void* d_ws, size_t ws_size,
                              hipStream_t stream) {
    const float* embeds  = (const float*)d_in[0];   // [20000,300]
    const float* states  = (const float*)d_in[1];   // [20000,400]
    const float* attn_W1 = (const float*)d_in[2];   // [400,150]
    const float* attn_b1 = (const float*)d_in[3];
    const float* attn_W2 = (const float*)d_in[4];   // [150,150]
    const float* attn_b2 = (const float*)d_in[5];
    const float* attn_W3 = (const float*)d_in[6];   // [150,1]
    const float* attn_b3 = (const float*)d_in[7];   // [1]
    const float* sc_W1   = (const float*)d_in[8];   // [1100,150]
    const float* sc_b1   = (const float*)d_in[9];
    const float* sc_W2   = (const float*)d_in[10];  // [150,150]
    const float* sc_b2   = (const float*)d_in[11];
    const float* sc_W3   = (const float*)d_in[12];  // [150,1]
    const float* sc_b3   = (const float*)d_in[13];  // [1]
    float* out = (float*)d_out;

    float* ws = (float*)d_ws;
    float* X1U    = ws;               // 3,000,000 floats: X1, later reused as U
    float* Vbuf   = ws + 3000000;     // 3,000,000
    float* Pbuf   = ws + 6000000;     // 3,000,000
    float* logits = ws + 9000000;     // 20,000
    // total 9,020,000 floats = 36.1 MB

    const int MB = T_LEN / 32;        // 625 blocks

    // Attention MLP layer 1: X1 = relu(states @ attn_W1 + attn_b1)
    gemm150<<<MB, 256, 0, stream>>>(states, attn_W1, attn_b1, X1U, 400, 1);
    // Attention tail: logits = relu(X1 @ attn_W2 + b2) @ attn_W3 + b3
    attn_tail<<<MB, 256, 0, stream>>>(X1U, attn_W2, attn_b2, attn_W3, attn_b3, logits);
    // U = states @ sc_W1[0:400,:] + sc_b1   (overwrites X1; stream-ordered)
    gemm150<<<MB, 256, 0, stream>>>(states, sc_W1, sc_b1, X1U, 400, 0);
    // V = states @ sc_W1[400:800,:]
    gemm150<<<MB, 256, 0, stream>>>(states, sc_W1 + 400 * HID, nullptr, Vbuf, 400, 0);
    // P = embeds @ sc_W1[800:1100,:]
    gemm150<<<MB, 256, 0, stream>>>(embeds, sc_W1 + 800 * HID, nullptr, Pbuf, 300, 0);

    // Span scoring, one launch per width n
    int off = 0;
    for (int n = 1; n <= MAXN; ++n) {
        int S = T_LEN - n + 1;
        int blocks = (S + 63) / 64;
        span_score<<<blocks, 256, 0, stream>>>(X1U, Vbuf, Pbuf, logits,
                                               sc_W2, sc_b2, sc_W3, sc_b3,
                                               out, n, S, off);
        off += S;
    }
}

// Round 2
// 897.699 us; speedup vs baseline: 2.0615x; 2.0615x over previous
//
#include <hip/hip_runtime.h>
#include <math.h>

#define T_LEN 20000
#define HID 150
#define BNP 160   // padded N for LDS B tiles

// ---------------------------------------------------------------------------
// big3: three GEMMs in one dispatch (grid.y selects output), BM=128, BK=32.
//   y=0: U = states @ sc_W1[0:400]   + sc_b1      (K=400)
//   y=1: V = states @ sc_W1[400:800]              (K=400)
//   y=2: P = embeds @ sc_W1[800:1100]             (K=300)
// 256 threads: rt=tid>>3 (4 rows each -> 128), ct=tid&7 (20 cols each -> 160).
// Per kk: 4 x ds_read_b32 (A, stride-38 pad => 2-way banking, free) +
//         5 x ds_read_b128 (B, conflict-free) feeding 80 FMAs.
// ---------------------------------------------------------------------------
__global__ __launch_bounds__(256) void big3(
    const float* __restrict__ states, const float* __restrict__ embeds,
    const float* __restrict__ scW1, const float* __restrict__ scb1,
    float* __restrict__ U, float* __restrict__ V, float* __restrict__ P)
{
    __shared__ float As[128][38];
    __shared__ float Bs[32][BNP];
    const int tid = threadIdx.x;
    const int m0 = blockIdx.x * 128;
    const int y = blockIdx.y;

    const float* A = (y == 2) ? embeds : states;
    const int K = (y == 2) ? 300 : 400;
    const float* B = scW1 + (long)y * 400 * HID;   // y=2 -> offset 800*150
    const float* bias = (y == 0) ? scb1 : nullptr;
    float* C = (y == 0) ? U : (y == 1) ? V : P;

    const int rt = tid >> 3;   // 0..31
    const int ct = tid & 7;    // 0..7

    float acc[4][20];
    #pragma unroll
    for (int r = 0; r < 4; ++r)
        #pragma unroll
        for (int q = 0; q < 20; ++q) acc[r][q] = 0.f;

    for (int k0 = 0; k0 < K; k0 += 32) {
        // A tile: 128 rows x 32 k = 1024 float4 loads
        #pragma unroll
        for (int it = 0; it < 4; ++it) {
            int f = tid + it * 256;
            int row = f >> 3, kq = f & 7;
            int gk = k0 + 4 * kq;
            int m = m0 + row; if (m > T_LEN - 1) m = T_LEN - 1;
            float4 v = make_float4(0.f, 0.f, 0.f, 0.f);
            if (gk < K) v = *(const float4*)&A[(long)m * K + gk];
            *(float2*)&As[row][4 * kq]     = make_float2(v.x, v.y);
            *(float2*)&As[row][4 * kq + 2] = make_float2(v.z, v.w);
        }
        // B tile: 32 x 150 (float2), zero-pad to 160 and beyond K
        #pragma unroll
        for (int it = 0; it < 10; ++it) {
            int t = tid + it * 256;            // 0..2559, need 32*80=2560
            int kk = t / 80, e2 = t - kk * 80;
            int e = 2 * e2;
            int gk = k0 + kk;
            float2 v = make_float2(0.f, 0.f);
            if (gk < K && e < HID) v = *(const float2*)&B[(long)gk * HID + e];
            *(float2*)&Bs[kk][e] = v;
        }
        __syncthreads();
        #pragma unroll
        for (int kk = 0; kk < 32; ++kk) {
            float a[4];
            #pragma unroll
            for (int r = 0; r < 4; ++r) a[r] = As[4 * rt + r][kk];
            float bv[20];
            #pragma unroll
            for (int q4 = 0; q4 < 5; ++q4)
                *(float4*)&bv[4 * q4] = *(const float4*)&Bs[kk][ct * 20 + 4 * q4];
            #pragma unroll
            for (int r = 0; r < 4; ++r)
                #pragma unroll
                for (int q = 0; q < 20; ++q)
                    acc[r][q] += a[r] * bv[q];
        }
        __syncthreads();
    }

    #pragma unroll
    for (int r = 0; r < 4; ++r) {
        int gm = m0 + 4 * rt + r;
        if (gm < T_LEN) {
            #pragma unroll
            for (int q2 = 0; q2 < 10; ++q2) {
                int e = ct * 20 + 2 * q2;
                if (e + 1 < HID) {
                    float2 v = make_float2(acc[r][2 * q2], acc[r][2 * q2 + 1]);
                    if (bias) { v.x += bias[e]; v.y += bias[e + 1]; }
                    *(float2*)&C[(long)gm * HID + e] = v;
                }
            }
        }
    }
}

// ---------------------------------------------------------------------------
// attn_fused: logits = relu(relu(states@W1+b1)@W2+b2)@W3+b3, 64 rows/block.
// Layer 1: K=400, BK=16 (exact). Layer 2: K=150 in 16-row chunks (Bs reused).
// ---------------------------------------------------------------------------
__global__ __launch_bounds__(256) void attn_fused(
    const float* __restrict__ states,
    const float* __restrict__ W1, const float* __restrict__ b1,
    const float* __restrict__ W2, const float* __restrict__ b2,
    const float* __restrict__ W3, const float* __restrict__ b3,
    float* __restrict__ logits)
{
    __shared__ float As[64][20];
    __shared__ float Bs[16][152];
    __shared__ float X1s[64][151];
    __shared__ float red[64][8];
    const int tid = threadIdx.x;
    const int m0 = blockIdx.x * 64;
    const int rt = tid >> 3;   // 0..31, 2 rows each
    const int ct = tid & 7;    // 20 cols each

    float acc[2][20];
    #pragma unroll
    for (int r = 0; r < 2; ++r)
        #pragma unroll
        for (int q = 0; q < 20; ++q) acc[r][q] = 0.f;

    for (int k0 = 0; k0 < 400; k0 += 16) {
        // A tile: 64 x 16 = 256 float4
        {
            int row = tid >> 2, kq = tid & 3;
            int gk = k0 + 4 * kq;
            int m = m0 + row; if (m > T_LEN - 1) m = T_LEN - 1;
            float4 v = *(const float4*)&states[(long)m * 400 + gk];
            *(float2*)&As[row][4 * kq]     = make_float2(v.x, v.y);
            *(float2*)&As[row][4 * kq + 2] = make_float2(v.z, v.w);
        }
        // B tile: 16 x 150 float2 (16*76=1216 slots)
        #pragma unroll
        for (int it = 0; it < 5; ++it) {
            int t = tid + it * 256;
            if (t < 16 * 76) {
                int kk = t / 76, e2 = t - kk * 76;
                int e = 2 * e2;
                float2 v = make_float2(0.f, 0.f);
                if (e < HID) v = *(const float2*)&W1[(long)(k0 + kk) * HID + e];
                *(float2*)&Bs[kk][e] = v;
            }
        }
        __syncthreads();
        #pragma unroll
        for (int kk = 0; kk < 16; ++kk) {
            float a[2];
            a[0] = As[2 * rt][kk];
            a[1] = As[2 * rt + 1][kk];
            float bv[20];
            #pragma unroll
            for (int q4 = 0; q4 < 5; ++q4)
                *(float4*)&bv[4 * q4] = *(const float4*)&Bs[kk][ct * 20 + 4 * q4];
            #pragma unroll
            for (int r = 0; r < 2; ++r)
                #pragma unroll
                for (int q = 0; q < 20; ++q)
                    acc[r][q] += a[r] * bv[q];
        }
        __syncthreads();
    }

    // X1 = relu(acc + b1) into LDS
    #pragma unroll
    for (int r = 0; r < 2; ++r) {
        int row = 2 * rt + r;
        #pragma unroll
        for (int q2 = 0; q2 < 10; ++q2) {
            int e = ct * 20 + 2 * q2;
            if (e + 1 < HID) {
                X1s[row][e]     = fmaxf(acc[r][2 * q2]     + b1[e],     0.f);
                X1s[row][e + 1] = fmaxf(acc[r][2 * q2 + 1] + b1[e + 1], 0.f);
            }
        }
    }
    __syncthreads();

    // Layer 2: K=150 in chunks of 16
    float acc2[2][20];
    #pragma unroll
    for (int r = 0; r < 2; ++r)
        #pragma unroll
        for (int q = 0; q < 20; ++q) acc2[r][q] = 0.f;

    for (int d0 = 0; d0 < HID; d0 += 16) {
        #pragma unroll
        for (int it = 0; it < 5; ++it) {
            int t = tid + it * 256;
            if (t < 16 * 76) {
                int kk = t / 76, e2 = t - kk * 76;
                int e = 2 * e2;
                float2 v = make_float2(0.f, 0.f);
                if (e < HID && d0 + kk < HID)
                    v = *(const float2*)&W2[(long)(d0 + kk) * HID + e];
                *(float2*)&Bs[kk][e] = v;
            }
        }
        __syncthreads();
        #pragma unroll
        for (int kk = 0; kk < 16; ++kk) {
            float a[2];
            a[0] = X1s[2 * rt][d0 + kk];       // OOB cols read garbage * 0
            a[1] = X1s[2 * rt + 1][d0 + kk];
            float bv[20];
            #pragma unroll
            for (int q4 = 0; q4 < 5; ++q4)
                *(float4*)&bv[4 * q4] = *(const float4*)&Bs[kk][ct * 20 + 4 * q4];
            #pragma unroll
            for (int r = 0; r < 2; ++r)
                #pragma unroll
                for (int q = 0; q < 20; ++q)
                    acc2[r][q] += a[r] * bv[q];
        }
        __syncthreads();
    }

    float partial[2] = {0.f, 0.f};
    #pragma unroll
    for (int r = 0; r < 2; ++r)
        #pragma unroll
        for (int q = 0; q < 20; ++q) {
            int e = ct * 20 + q;
            if (e < HID) {
                float h2 = fmaxf(acc2[r][q] + b2[e], 0.f);
                partial[r] += h2 * W3[e];
            }
        }
    #pragma unroll
    for (int r = 0; r < 2; ++r) red[2 * rt + r][ct] = partial[r];
    __syncthreads();
    if (tid < 64) {
        int m = m0 + tid;
        if (m < T_LEN) {
            float s = b3[0];
            #pragma unroll
            for (int t = 0; t < 8; ++t) s += red[tid][t];
            logits[m] = s;
        }
    }
}

// ---------------------------------------------------------------------------
// span_score: ALL widths in one dispatch. grid = (313, 10); n = y+1.
// 64 spans/block; phase1 builds h1 (pre-GEMM-folded first layer), phase2 does
// h1 @ sc_W2 with 2x20 microtile + b128 B reads, phase3 relu-dot-W3 reduce.
// ---------------------------------------------------------------------------
__global__ __launch_bounds__(256) void span_score(
    const float* __restrict__ U, const float* __restrict__ V,
    const float* __restrict__ P, const float* __restrict__ logits,
    const float* __restrict__ W2, const float* __restrict__ b2,
    const float* __restrict__ W3, const float* __restrict__ b3,
    float* __restrict__ out)
{
    __shared__ float h1[64][151];
    __shared__ float W2c[25][BNP];
    __shared__ float wbuf[64][10];
    __shared__ float b2s[152];
    __shared__ float W3s[152];
    __shared__ float red[64][8];

    const int tid = threadIdx.x;
    const int n = blockIdx.y + 1;
    const int S = T_LEN - n + 1;
    const int s0 = blockIdx.x * 64;
    const int out_off = (n - 1) * (T_LEN + 1) - (n - 1) * n / 2;

    for (int t = tid; t < HID; t += 256) { b2s[t] = b2[t]; W3s[t] = W3[t]; }

    if (tid < 64) {
        int s = s0 + tid; if (s > S - 1) s = S - 1;
        float mx = -1e30f;
        for (int j = 0; j < n; ++j) mx = fmaxf(mx, logits[s + j]);
        float sum = 0.f;
        for (int j = 0; j < n; ++j) sum += expf(logits[s + j] - mx);
        float inv = 1.f / sum;
        for (int j = 0; j < n; ++j) wbuf[tid][j] = expf(logits[s + j] - mx) * inv;
    }
    __syncthreads();

    // phase 1: h1[i][d] = relu(U[s]+V[s+n-1]+sum_j w_j P[s+j])
    for (int idx = tid; idx < 64 * HID; idx += 256) {
        int i = idx / HID, d = idx - i * HID;
        int s = s0 + i; if (s > S - 1) s = S - 1;
        float pre = U[(long)s * HID + d] + V[(long)(s + n - 1) * HID + d];
        for (int j = 0; j < n; ++j) pre += wbuf[i][j] * P[(long)(s + j) * HID + d];
        h1[i][d] = fmaxf(pre, 0.f);
    }
    __syncthreads();

    // phase 2: h2 = h1 @ W2, 2 rows x 20 cols per thread
    const int rt = tid >> 3, ct = tid & 7;
    float acc[2][20];
    #pragma unroll
    for (int r = 0; r < 2; ++r)
        #pragma unroll
        for (int q = 0; q < 20; ++q) acc[r][q] = 0.f;

    for (int d0 = 0; d0 < HID; d0 += 25) {
        #pragma unroll
        for (int it = 0; it < 8; ++it) {
            int t = tid + it * 256;              // need 25*80 = 2000
            if (t < 2000) {
                int kk = t / 80, e2 = t - kk * 80;
                int e = 2 * e2;
                float2 v = make_float2(0.f, 0.f);
                if (e < HID) v = *(const float2*)&W2[(long)(d0 + kk) * HID + e];
                *(float2*)&W2c[kk][e] = v;
            }
        }
        __syncthreads();
        #pragma unroll
        for (int dd = 0; dd < 25; ++dd) {
            float a[2];
            a[0] = h1[2 * rt][d0 + dd];
            a[1] = h1[2 * rt + 1][d0 + dd];
            float bv[20];
            #pragma unroll
            for (int q4 = 0; q4 < 5; ++q4)
                *(float4*)&bv[4 * q4] = *(const float4*)&W2c[dd][ct * 20 + 4 * q4];
            #pragma unroll
            for (int r = 0; r < 2; ++r)
                #pragma unroll
                for (int q = 0; q < 20; ++q)
                    acc[r][q] += a[r] * bv[q];
        }
        __syncthreads();
    }

    // phase 3: score = relu(h2+b2) . W3 + b3
    float partial[2] = {0.f, 0.f};
    #pragma unroll
    for (int r = 0; r < 2; ++r)
        #pragma unroll
        for (int q = 0; q < 20; ++q) {
            int e = ct * 20 + q;
            if (e < HID) {
                float h2 = fmaxf(acc[r][q] + b2s[e], 0.f);
                partial[r] += h2 * W3s[e];
            }
        }
    #pragma unroll
    for (int r = 0; r < 2; ++r) red[2 * rt + r][ct] = partial[r];
    __syncthreads();
    if (tid < 64) {
        int s = s0 + tid;
        if (s < S) {
            float sc = b3[0];
            #pragma unroll
            for (int t = 0; t < 8; ++t) sc += red[tid][t];
            out[out_off + s] = sc;
        }
    }
}

// ---------------------------------------------------------------------------
extern "C" void kernel_launch(void* const* d_in, const int* in_sizes, int n_in,
                              void* d_out, int out_size, void* d_ws, size_t ws_size,
                              hipStream_t stream) {
    const float* embeds  = (const float*)d_in[0];   // [20000,300]
    const float* states  = (const float*)d_in[1];   // [20000,400]
    const float* attn_W1 = (const float*)d_in[2];   // [400,150]
    const float* attn_b1 = (const float*)d_in[3];
    const float* attn_W2 = (const float*)d_in[4];   // [150,150]
    const float* attn_b2 = (const float*)d_in[5];
    const float* attn_W3 = (const float*)d_in[6];   // [150,1]
    const float* attn_b3 = (const float*)d_in[7];   // [1]
    const float* sc_W1   = (const float*)d_in[8];   // [1100,150]
    const float* sc_b1   = (const float*)d_in[9];
    const float* sc_W2   = (const float*)d_in[10];  // [150,150]
    const float* sc_b2   = (const float*)d_in[11];
    const float* sc_W3   = (const float*)d_in[12];  // [150,1]
    const float* sc_b3   = (const float*)d_in[13];  // [1]
    float* out = (float*)d_out;

    float* ws = (float*)d_ws;
    float* Ubuf   = ws;               // 3,000,000 floats
    float* Vbuf   = ws + 3000000;     // 3,000,000
    float* Pbuf   = ws + 6000000;     // 3,000,000
    float* logits = ws + 9000000;     // 20,000  (total 36.1 MB)

    // U, V, P in one dispatch (independent of attention path)
    big3<<<dim3(157, 3), 256, 0, stream>>>(states, embeds, sc_W1, sc_b1,
                                           Ubuf, Vbuf, Pbuf);
    // full attention MLP -> per-token logits
    attn_fused<<<313, 256, 0, stream>>>(states, attn_W1, attn_b1,
                                        attn_W2, attn_b2, attn_W3, attn_b3,
                                        logits);
    // all span widths in one dispatch
    span_score<<<dim3(313, 10), 256, 0, stream>>>(Ubuf, Vbuf, Pbuf, logits,
                                                  sc_W2, sc_b2, sc_W3, sc_b3,
                                                  out);
}

// Round 3
// 763.189 us; speedup vs baseline: 2.4249x; 1.1762x over previous
//
#include <hip/hip_runtime.h>
#include <math.h>

#define T_LEN 20000
#define HID 150

typedef __attribute__((ext_vector_type(8))) __bf16 bf16x8;
typedef __attribute__((ext_vector_type(4))) float f32x4;

__device__ __forceinline__ short f2bf(float f) {
    unsigned u = __float_as_uint(f);
    u = (u + 0x7fff + ((u >> 16) & 1)) >> 16;   // round-to-nearest-even
    return (short)u;
}

// ---------------------------------------------------------------------------
// big3: U/V/P = {states,states,embeds} @ sc_W1 slices. BM=128, BK=32.
// A tile stored TRANSPOSED in LDS: AsT[k][row] -> one broadcast ds_read_b128
// per kk instead of 4 conflicted b32 reads.
// ---------------------------------------------------------------------------
__global__ __launch_bounds__(256) void big3(
    const float* __restrict__ states, const float* __restrict__ embeds,
    const float* __restrict__ scW1, const float* __restrict__ scb1,
    float* __restrict__ U, float* __restrict__ V, float* __restrict__ P)
{
    __shared__ float AsT[32][132];   // [k][row], pad 132 -> conflict-free b128 reads
    __shared__ float Bs[32][160];
    const int tid = threadIdx.x;
    const int m0 = blockIdx.x * 128;
    const int y = blockIdx.y;

    const float* A = (y == 2) ? embeds : states;
    const int K = (y == 2) ? 300 : 400;
    const float* B = scW1 + (long)y * 400 * HID;
    const float* bias = (y == 0) ? scb1 : nullptr;
    float* C = (y == 0) ? U : (y == 1) ? V : P;

    const int rt = tid >> 3;   // 0..31 -> 4 rows
    const int ct = tid & 7;    // 0..7  -> 20 cols

    float acc[4][20];
    #pragma unroll
    for (int r = 0; r < 4; ++r)
        #pragma unroll
        for (int q = 0; q < 20; ++q) acc[r][q] = 0.f;

    for (int k0 = 0; k0 < K; k0 += 32) {
        #pragma unroll
        for (int it = 0; it < 4; ++it) {
            int f = tid + it * 256;
            int row = f >> 3, kq = f & 7;
            int gk = k0 + 4 * kq;
            int m = m0 + row; if (m > T_LEN - 1) m = T_LEN - 1;
            float4 v = make_float4(0.f, 0.f, 0.f, 0.f);
            if (gk < K) v = *(const float4*)&A[(long)m * K + gk];
            AsT[4 * kq + 0][row] = v.x;
            AsT[4 * kq + 1][row] = v.y;
            AsT[4 * kq + 2][row] = v.z;
            AsT[4 * kq + 3][row] = v.w;
        }
        #pragma unroll
        for (int it = 0; it < 10; ++it) {
            int t = tid + it * 256;            // 32*80 = 2560
            int kk = t / 80, e2 = t - kk * 80;
            int e = 2 * e2;
            int gk = k0 + kk;
            float2 v = make_float2(0.f, 0.f);
            if (gk < K && e < HID) v = *(const float2*)&B[(long)gk * HID + e];
            *(float2*)&Bs[kk][e] = v;
        }
        __syncthreads();
        #pragma unroll
        for (int kk = 0; kk < 32; ++kk) {
            float4 a4 = *(const float4*)&AsT[kk][4 * rt];
            float a[4] = {a4.x, a4.y, a4.z, a4.w};
            float bv[20];
            #pragma unroll
            for (int q4 = 0; q4 < 5; ++q4)
                *(float4*)&bv[4 * q4] = *(const float4*)&Bs[kk][ct * 20 + 4 * q4];
            #pragma unroll
            for (int r = 0; r < 4; ++r)
                #pragma unroll
                for (int q = 0; q < 20; ++q)
                    acc[r][q] += a[r] * bv[q];
        }
        __syncthreads();
    }

    #pragma unroll
    for (int r = 0; r < 4; ++r) {
        int gm = m0 + 4 * rt + r;
        if (gm < T_LEN) {
            #pragma unroll
            for (int q2 = 0; q2 < 10; ++q2) {
                int e = ct * 20 + 2 * q2;
                if (e + 1 < HID) {
                    float2 v = make_float2(acc[r][2 * q2], acc[r][2 * q2 + 1]);
                    if (bias) { v.x += bias[e]; v.y += bias[e + 1]; }
                    *(float2*)&C[(long)gm * HID + e] = v;
                }
            }
        }
    }
}

// ---------------------------------------------------------------------------
// attn_fused: logits = relu(relu(states@W1+b1)@W2+b2)@W3+b3, 64 rows/block.
// A tile transposed in LDS -> broadcast ds_read_b64.
// ---------------------------------------------------------------------------
__global__ __launch_bounds__(256) void attn_fused(
    const float* __restrict__ states,
    const float* __restrict__ W1, const float* __restrict__ b1,
    const float* __restrict__ W2, const float* __restrict__ b2,
    const float* __restrict__ W3, const float* __restrict__ b3,
    float* __restrict__ logits)
{
    __shared__ float AsT[16][68];    // [k][row]
    __shared__ float Bs[16][152];
    __shared__ float X1s[64][151];
    __shared__ float red[64][8];
    const int tid = threadIdx.x;
    const int m0 = blockIdx.x * 64;
    const int rt = tid >> 3;   // 0..31, 2 rows each
    const int ct = tid & 7;    // 20 cols each

    float acc[2][20];
    #pragma unroll
    for (int r = 0; r < 2; ++r)
        #pragma unroll
        for (int q = 0; q < 20; ++q) acc[r][q] = 0.f;

    for (int k0 = 0; k0 < 400; k0 += 16) {
        {
            int row = tid >> 2, kq = tid & 3;
            int gk = k0 + 4 * kq;
            int m = m0 + row; if (m > T_LEN - 1) m = T_LEN - 1;
            float4 v = *(const float4*)&states[(long)m * 400 + gk];
            AsT[4 * kq + 0][row] = v.x;
            AsT[4 * kq + 1][row] = v.y;
            AsT[4 * kq + 2][row] = v.z;
            AsT[4 * kq + 3][row] = v.w;
        }
        #pragma unroll
        for (int it = 0; it < 5; ++it) {
            int t = tid + it * 256;
            if (t < 16 * 76) {
                int kk = t / 76, e2 = t - kk * 76;
                int e = 2 * e2;
                float2 v = make_float2(0.f, 0.f);
                if (e < HID) v = *(const float2*)&W1[(long)(k0 + kk) * HID + e];
                *(float2*)&Bs[kk][e] = v;
            }
        }
        __syncthreads();
        #pragma unroll
        for (int kk = 0; kk < 16; ++kk) {
            float2 a2 = *(const float2*)&AsT[kk][2 * rt];
            float bv[20];
            #pragma unroll
            for (int q4 = 0; q4 < 5; ++q4)
                *(float4*)&bv[4 * q4] = *(const float4*)&Bs[kk][ct * 20 + 4 * q4];
            #pragma unroll
            for (int q = 0; q < 20; ++q) {
                acc[0][q] += a2.x * bv[q];
                acc[1][q] += a2.y * bv[q];
            }
        }
        __syncthreads();
    }

    #pragma unroll
    for (int r = 0; r < 2; ++r) {
        int row = 2 * rt + r;
        #pragma unroll
        for (int q2 = 0; q2 < 10; ++q2) {
            int e = ct * 20 + 2 * q2;
            if (e + 1 < HID) {
                X1s[row][e]     = fmaxf(acc[r][2 * q2]     + b1[e],     0.f);
                X1s[row][e + 1] = fmaxf(acc[r][2 * q2 + 1] + b1[e + 1], 0.f);
            }
        }
    }
    __syncthreads();

    float acc2[2][20];
    #pragma unroll
    for (int r = 0; r < 2; ++r)
        #pragma unroll
        for (int q = 0; q < 20; ++q) acc2[r][q] = 0.f;

    for (int d0 = 0; d0 < HID; d0 += 16) {
        #pragma unroll
        for (int it = 0; it < 5; ++it) {
            int t = tid + it * 256;
            if (t < 16 * 76) {
                int kk = t / 76, e2 = t - kk * 76;
                int e = 2 * e2;
                float2 v = make_float2(0.f, 0.f);
                if (e < HID && d0 + kk < HID)
                    v = *(const float2*)&W2[(long)(d0 + kk) * HID + e];
                *(float2*)&Bs[kk][e] = v;
            }
        }
        __syncthreads();
        #pragma unroll
        for (int kk = 0; kk < 16; ++kk) {
            float a0 = X1s[2 * rt][d0 + kk];
            float a1 = X1s[2 * rt + 1][d0 + kk];
            float bv[20];
            #pragma unroll
            for (int q4 = 0; q4 < 5; ++q4)
                *(float4*)&bv[4 * q4] = *(const float4*)&Bs[kk][ct * 20 + 4 * q4];
            #pragma unroll
            for (int q = 0; q < 20; ++q) {
                acc2[0][q] += a0 * bv[q];
                acc2[1][q] += a1 * bv[q];
            }
        }
        __syncthreads();
    }

    float partial[2] = {0.f, 0.f};
    #pragma unroll
    for (int r = 0; r < 2; ++r)
        #pragma unroll
        for (int q = 0; q < 20; ++q) {
            int e = ct * 20 + q;
            if (e < HID) {
                float h2 = fmaxf(acc2[r][q] + b2[e], 0.f);
                partial[r] += h2 * W3[e];
            }
        }
    #pragma unroll
    for (int r = 0; r < 2; ++r) red[2 * rt + r][ct] = partial[r];
    __syncthreads();
    if (tid < 64) {
        int m = m0 + tid;
        if (m < T_LEN) {
            float s = b3[0];
            #pragma unroll
            for (int t = 0; t < 8; ++t) s += red[tid][t];
            logits[m] = s;
        }
    }
}

// ---------------------------------------------------------------------------
// w2prep: W2 [150x150] fp32 -> W2t bf16 [160][168] transposed + zero-padded.
// W2t[n][k] = bf16(W2[k][n]).
// ---------------------------------------------------------------------------
__global__ __launch_bounds__(256) void w2prep(const float* __restrict__ W2,
                                              short* __restrict__ W2t)
{
    int t = blockIdx.x * 256 + threadIdx.x;
    if (t < 160 * 168) {
        int nn = t / 168, k = t - nn * 168;
        float v = (nn < HID && k < HID) ? W2[(long)k * HID + nn] : 0.f;
        W2t[t] = f2bf(v);
    }
}

// ---------------------------------------------------------------------------
// span_mfma: all widths, grid (313, 10). 64 spans/block, 4 waves.
// Phase 1: h1 fp32 -> bf16 LDS [64][168]. Phase 2: MFMA 16x16x32 bf16,
// wave w owns m-tile w (16 spans); loops 10 n-tiles x 5 k-steps with A-frags
// preloaded. Epilogue: relu(h2+b2).W3 accumulated per-lane, shfl-xor reduce.
// ---------------------------------------------------------------------------
__global__ __launch_bounds__(256) void span_mfma(
    const float* __restrict__ U, const float* __restrict__ V,
    const float* __restrict__ P, const float* __restrict__ logits,
    const short* __restrict__ W2t, const float* __restrict__ b2,
    const float* __restrict__ W3, const float* __restrict__ b3,
    float* __restrict__ out)
{
    __shared__ short W2s[160 * 168];   // 53760 B
    __shared__ short h1s[64 * 168];    // 21504 B
    __shared__ float wbuf[64][10];
    __shared__ float b2s[160];
    __shared__ float W3s[160];

    const int tid = threadIdx.x;
    const int n = blockIdx.y + 1;
    const int S = T_LEN - n + 1;
    const int s0 = blockIdx.x * 64;
    const int out_off = (n - 1) * (T_LEN + 1) - (n - 1) * n / 2;

    // stage W2t (already padded bf16) as straight float4 copy: 3360 x 16B
    {
        const float4* wg = (const float4*)W2t;
        float4* wl = (float4*)W2s;
        for (int t = tid; t < 3360; t += 256) wl[t] = wg[t];
    }
    for (int t = tid; t < 160; t += 256) {
        b2s[t] = (t < HID) ? b2[t] : 0.f;
        W3s[t] = (t < HID) ? W3[t] : 0.f;
    }
    // zero h1 k-padding [150..168)
    for (int t = tid; t < 64 * 18; t += 256) {
        int i = t / 18, d = t - i * 18;
        h1s[i * 168 + 150 + d] = 0;
    }
    if (tid < 64) {
        int s = s0 + tid; if (s > S - 1) s = S - 1;
        float mx = -1e30f;
        for (int j = 0; j < n; ++j) mx = fmaxf(mx, logits[s + j]);
        float sum = 0.f;
        float ex[10];
        for (int j = 0; j < n; ++j) { ex[j] = expf(logits[s + j] - mx); sum += ex[j]; }
        float inv = 1.f / sum;
        for (int j = 0; j < n; ++j) wbuf[tid][j] = ex[j] * inv;
    }
    __syncthreads();

    // phase 1: h1 = relu(U[s] + V[s+n-1] + sum_j w_j P[s+j]) -> bf16
    for (int idx = tid; idx < 64 * HID; idx += 256) {
        int i = idx / HID, d = idx - i * HID;
        int s = s0 + i; if (s > S - 1) s = S - 1;
        float pre = U[(long)s * HID + d] + V[(long)(s + n - 1) * HID + d];
        for (int j = 0; j < n; ++j) pre += wbuf[i][j] * P[(long)(s + j) * HID + d];
        h1s[i * 168 + d] = f2bf(fmaxf(pre, 0.f));
    }
    __syncthreads();

    // phase 2: MFMA
    const int w = tid >> 6;        // wave id = m-tile (16 spans)
    const int lane = tid & 63;
    const int ml = lane & 15;      // A row / B col within tile
    const int kg = lane >> 4;      // k-group

    bf16x8 af[5];
    #pragma unroll
    for (int ks = 0; ks < 5; ++ks)
        af[ks] = *(const bf16x8*)&h1s[(16 * w + ml) * 168 + ks * 32 + kg * 8];

    float score[4] = {0.f, 0.f, 0.f, 0.f};
    #pragma unroll
    for (int nt = 0; nt < 10; ++nt) {
        f32x4 acc = {0.f, 0.f, 0.f, 0.f};
        #pragma unroll
        for (int ks = 0; ks < 5; ++ks) {
            bf16x8 bf = *(const bf16x8*)&W2s[(nt * 16 + ml) * 168 + ks * 32 + kg * 8];
            acc = __builtin_amdgcn_mfma_f32_16x16x32_bf16(af[ks], bf, acc, 0, 0, 0);
        }
        int col = nt * 16 + ml;
        float b2v = b2s[col], w3v = W3s[col];
        #pragma unroll
        for (int r = 0; r < 4; ++r)
            score[r] += fmaxf(acc[r] + b2v, 0.f) * w3v;
    }
    #pragma unroll
    for (int r = 0; r < 4; ++r) {
        score[r] += __shfl_xor(score[r], 1);
        score[r] += __shfl_xor(score[r], 2);
        score[r] += __shfl_xor(score[r], 4);
        score[r] += __shfl_xor(score[r], 8);
    }
    if (ml == 0) {
        float bb = b3[0];
        #pragma unroll
        for (int r = 0; r < 4; ++r) {
            int s = s0 + 16 * w + kg * 4 + r;   // D row = kg*4 + r
            if (s < S) out[out_off + s] = score[r] + bb;
        }
    }
}

// ---------------------------------------------------------------------------
extern "C" void kernel_launch(void* const* d_in, const int* in_sizes, int n_in,
                              void* d_out, int out_size, void* d_ws, size_t ws_size,
                              hipStream_t stream) {
    const float* embeds  = (const float*)d_in[0];
    const float* states  = (const float*)d_in[1];
    const float* attn_W1 = (const float*)d_in[2];
    const float* attn_b1 = (const float*)d_in[3];
    const float* attn_W2 = (const float*)d_in[4];
    const float* attn_b2 = (const float*)d_in[5];
    const float* attn_W3 = (const float*)d_in[6];
    const float* attn_b3 = (const float*)d_in[7];
    const float* sc_W1   = (const float*)d_in[8];
    const float* sc_b1   = (const float*)d_in[9];
    const float* sc_W2   = (const float*)d_in[10];
    const float* sc_b2   = (const float*)d_in[11];
    const float* sc_W3   = (const float*)d_in[12];
    const float* sc_b3   = (const float*)d_in[13];
    float* out = (float*)d_out;

    float* ws = (float*)d_ws;
    float* Ubuf   = ws;               // 3,000,000 floats
    float* Vbuf   = ws + 3000000;
    float* Pbuf   = ws + 6000000;
    float* logits = ws + 9000000;     // 20,000
    short* W2t    = (short*)(ws + 9020000);  // 26,880 shorts (53.76 KB)

    w2prep<<<105, 256, 0, stream>>>(sc_W2, W2t);
    big3<<<dim3(157, 3), 256, 0, stream>>>(states, embeds, sc_W1, sc_b1,
                                           Ubuf, Vbuf, Pbuf);
    attn_fused<<<313, 256, 0, stream>>>(states, attn_W1, attn_b1,
                                        attn_W2, attn_b2, attn_W3, attn_b3,
                                        logits);
    span_mfma<<<dim3(313, 10), 256, 0, stream>>>(Ubuf, Vbuf, Pbuf, logits,
                                                 W2t, sc_b2, sc_W3, sc_b3,
                                                 out);
}

// Round 4
// 298.708 us; speedup vs baseline: 6.1954x; 2.5550x over previous
//
#include <hip/hip_runtime.h>
#include <hip/hip_bf16.h>
#include <math.h>

#define T_LEN 20000
#define HID 150

typedef __attribute__((ext_vector_type(8))) __bf16 bf16x8;
typedef __attribute__((ext_vector_type(4))) float f32x4;

// scalar fp32 -> bf16 (RNE), verified in round 3
__device__ __forceinline__ short f2bf(float f) {
    unsigned u = __float_as_uint(f);
    u = (u + 0x7fff + ((u >> 16) & 1)) >> 16;
    return (short)u;
}

// packed pair via hw cvt
__device__ __forceinline__ unsigned pk2(float a, float b) {
    __hip_bfloat162 h = __float22bfloat162_rn(make_float2(a, b));
    return *(unsigned*)&h;
}

__device__ __forceinline__ bf16x8 cvt8(float4 a, float4 b) {
    union { unsigned u[4]; bf16x8 v; } r;
    r.u[0] = pk2(a.x, a.y);
    r.u[1] = pk2(a.z, a.w);
    r.u[2] = pk2(b.x, b.y);
    r.u[3] = pk2(b.z, b.w);
    return r.v;
}

// ---------------------------------------------------------------------------
// wprep: cast + transpose all weight matrices to bf16 [n][k] layouts.
// Region layout in shorts:
//   [0,66560)        Bt0 [160][416]  sc_W1 rows 0..399   (U)
//   [66560,133120)   Bt1 [160][416]  sc_W1 rows 400..799 (V)
//   [133120,199680)  Bt2 [160][416]  sc_W1 rows 800..1099 (P, K=300)
//   [199680,266240)  At1 [160][416]  attn_W1
//   [266240,291840)  At2 [160][160]  attn_W2 (K=150 pad 160)
//   [291840,318720)  W2t [160][168]  sc_W2  (K=150 pad 168)
// ---------------------------------------------------------------------------
__global__ __launch_bounds__(256) void wprep(
    const float* __restrict__ sc_W1, const float* __restrict__ attn_W1,
    const float* __restrict__ attn_W2, const float* __restrict__ sc_W2,
    short* __restrict__ wbf)
{
    int t = blockIdx.x * 256 + threadIdx.x;
    if (t >= 318720) return;
    float v = 0.f;
    if (t < 199680) {
        int y = t / 66560, r = t - y * 66560;
        int nn = r / 416, k = r - nn * 416;
        int Kv = (y == 2) ? 300 : 400;
        if (nn < HID && k < Kv) v = sc_W1[(long)(y * 400 + k) * HID + nn];
    } else if (t < 266240) {
        int r = t - 199680;
        int nn = r / 416, k = r - nn * 416;
        if (nn < HID && k < 400) v = attn_W1[(long)k * HID + nn];
    } else if (t < 291840) {
        int r = t - 266240;
        int nn = r / 160, k = r - nn * 160;
        if (nn < HID && k < HID) v = attn_W2[(long)k * HID + nn];
    } else {
        int r = t - 291840;
        int nn = r / 168, k = r - nn * 168;
        if (nn < HID && k < HID) v = sc_W2[(long)k * HID + nn];
    }
    wbf[t] = f2bf(v);
}

// ---------------------------------------------------------------------------
// big3_mfma: U/V/P[20000][160] fp32 (stride 160, cols 150..159 zeroed).
// grid (313, 3). No LDS: A-frags from fp32 global (float4 x2 + cvt),
// B-frags from bf16 transposed weights (L2-resident).
// Wave w owns rows m0+16w..+15; 10 n-tiles of 16; K stepped by 32.
// ---------------------------------------------------------------------------
__global__ __launch_bounds__(256) void big3_mfma(
    const float* __restrict__ states, const float* __restrict__ embeds,
    const short* __restrict__ wbf, const float* __restrict__ scb1,
    float* __restrict__ U, float* __restrict__ V, float* __restrict__ P)
{
    const int tid = threadIdx.x;
    const int w = tid >> 6, lane = tid & 63;
    const int ml = lane & 15, kg = lane >> 4;
    const int m0 = blockIdx.x * 64;
    const int y = blockIdx.y;

    const float* A = (y == 2) ? embeds : states;
    const int Kdim = (y == 2) ? 300 : 400;
    const int Ksteps = (y == 2) ? 10 : 13;
    const short* Bt = wbf + (long)y * 66560;
    float* C = (y == 0) ? U : (y == 1) ? V : P;

    int arow = m0 + 16 * w + ml; if (arow > T_LEN - 1) arow = T_LEN - 1;
    const float* Arow = A + (long)arow * Kdim;

    f32x4 acc[10];
    #pragma unroll
    for (int nt = 0; nt < 10; ++nt) acc[nt] = (f32x4){0.f, 0.f, 0.f, 0.f};

    for (int ks = 0; ks < Ksteps; ++ks) {
        int k = ks * 32 + kg * 8;
        float4 a0 = make_float4(0.f, 0.f, 0.f, 0.f);
        float4 a1 = make_float4(0.f, 0.f, 0.f, 0.f);
        if (k + 4 <= Kdim) a0 = *(const float4*)&Arow[k];
        if (k + 8 <= Kdim) a1 = *(const float4*)&Arow[k + 4];
        bf16x8 af = cvt8(a0, a1);
        #pragma unroll
        for (int nt = 0; nt < 10; ++nt) {
            bf16x8 bf = *(const bf16x8*)&Bt[(long)(nt * 16 + ml) * 416 + k];
            acc[nt] = __builtin_amdgcn_mfma_f32_16x16x32_bf16(af, bf, acc[nt], 0, 0, 0);
        }
    }

    const bool has_bias = (y == 0);
    #pragma unroll
    for (int nt = 0; nt < 10; ++nt) {
        int col = nt * 16 + ml;
        float bv = (has_bias && col < HID) ? scb1[col] : 0.f;
        #pragma unroll
        for (int r = 0; r < 4; ++r) {
            int gm = m0 + 16 * w + kg * 4 + r;
            if (gm < T_LEN) {
                float v = (col < HID) ? acc[nt][r] + bv : 0.f;
                C[(long)gm * 160 + col] = v;
            }
        }
    }
}

// ---------------------------------------------------------------------------
// attn_mfma: logits = relu(relu(states@W1+b1)@W2+b2)@W3+b3, 64 rows/block.
// Layer 1 MFMA (K=400 pad 416) -> h bf16 LDS [64][168]; layer 2 MFMA (K=160,
// h pad-zeroed); epilogue relu-dot-W3, shfl-reduce over 16 cols-lanes.
// ---------------------------------------------------------------------------
__global__ __launch_bounds__(256) void attn_mfma(
    const float* __restrict__ states, const short* __restrict__ At1,
    const float* __restrict__ b1, const short* __restrict__ At2,
    const float* __restrict__ b2, const float* __restrict__ W3,
    const float* __restrict__ b3, float* __restrict__ logits)
{
    __shared__ short h1s[64 * 168];
    const int tid = threadIdx.x;
    const int w = tid >> 6, lane = tid & 63;
    const int ml = lane & 15, kg = lane >> 4;
    const int m0 = blockIdx.x * 64;

    int arow = m0 + 16 * w + ml; if (arow > T_LEN - 1) arow = T_LEN - 1;
    const float* Arow = states + (long)arow * 400;

    f32x4 acc[10];
    #pragma unroll
    for (int nt = 0; nt < 10; ++nt) acc[nt] = (f32x4){0.f, 0.f, 0.f, 0.f};

    for (int ks = 0; ks < 13; ++ks) {
        int k = ks * 32 + kg * 8;
        float4 a0 = make_float4(0.f, 0.f, 0.f, 0.f);
        float4 a1 = make_float4(0.f, 0.f, 0.f, 0.f);
        if (k + 4 <= 400) a0 = *(const float4*)&Arow[k];
        if (k + 8 <= 400) a1 = *(const float4*)&Arow[k + 4];
        bf16x8 af = cvt8(a0, a1);
        #pragma unroll
        for (int nt = 0; nt < 10; ++nt) {
            bf16x8 bf = *(const bf16x8*)&At1[(long)(nt * 16 + ml) * 416 + k];
            acc[nt] = __builtin_amdgcn_mfma_f32_16x16x32_bf16(af, bf, acc[nt], 0, 0, 0);
        }
    }

    // h = relu(acc + b1) -> bf16 LDS (cols 150..159 zero; k-reads stop at 160)
    #pragma unroll
    for (int nt = 0; nt < 10; ++nt) {
        int col = nt * 16 + ml;
        float bv = (col < HID) ? b1[col] : 0.f;
        #pragma unroll
        for (int r = 0; r < 4; ++r) {
            int row = kg * 4 + r;
            float v = (col < HID) ? fmaxf(acc[nt][r] + bv, 0.f) : 0.f;
            h1s[(16 * w + row) * 168 + col] = f2bf(v);
        }
    }
    __syncthreads();

    // layer 2: K = 160
    f32x4 acc2[10];
    #pragma unroll
    for (int nt = 0; nt < 10; ++nt) acc2[nt] = (f32x4){0.f, 0.f, 0.f, 0.f};
    bf16x8 af2[5];
    #pragma unroll
    for (int ks = 0; ks < 5; ++ks)
        af2[ks] = *(const bf16x8*)&h1s[(16 * w + ml) * 168 + ks * 32 + kg * 8];
    #pragma unroll
    for (int nt = 0; nt < 10; ++nt) {
        #pragma unroll
        for (int ks = 0; ks < 5; ++ks) {
            bf16x8 bf = *(const bf16x8*)&At2[(long)(nt * 16 + ml) * 160 + ks * 32 + kg * 8];
            acc2[nt] = __builtin_amdgcn_mfma_f32_16x16x32_bf16(af2[ks], bf, acc2[nt], 0, 0, 0);
        }
    }

    float score[4] = {0.f, 0.f, 0.f, 0.f};
    #pragma unroll
    for (int nt = 0; nt < 10; ++nt) {
        int col = nt * 16 + ml;
        float b2v = (col < HID) ? b2[col] : 0.f;
        float w3v = (col < HID) ? W3[col] : 0.f;
        #pragma unroll
        for (int r = 0; r < 4; ++r)
            score[r] += fmaxf(acc2[nt][r] + b2v, 0.f) * w3v;
    }
    #pragma unroll
    for (int r = 0; r < 4; ++r) {
        score[r] += __shfl_xor(score[r], 1);
        score[r] += __shfl_xor(score[r], 2);
        score[r] += __shfl_xor(score[r], 4);
        score[r] += __shfl_xor(score[r], 8);
    }
    if (ml == 0) {
        float bb = b3[0];
        #pragma unroll
        for (int r = 0; r < 4; ++r) {
            int gm = m0 + 16 * w + kg * 4 + r;
            if (gm < T_LEN) logits[gm] = score[r] + bb;
        }
    }
}

// ---------------------------------------------------------------------------
// span_mfma: grid (10, 313) — width fastest => 10 consecutive blocks share
// one chunk's U/V/P rows (L2/LLC locality). 64 spans/block, 4 waves.
// Phase 1: float4 gather (stride-160 padded U/V/P) -> h1 bf16 LDS [64][168].
// Phase 2: MFMA vs W2t straight from global (L2-resident, no LDS staging).
// ---------------------------------------------------------------------------
__global__ __launch_bounds__(256) void span_mfma(
    const float* __restrict__ U, const float* __restrict__ V,
    const float* __restrict__ Pb, const float* __restrict__ logits,
    const short* __restrict__ W2t, const float* __restrict__ b2,
    const float* __restrict__ W3, const float* __restrict__ b3,
    float* __restrict__ out)
{
    __shared__ short h1s[64 * 168];
    __shared__ float wbuf[64][10];

    const int tid = threadIdx.x;
    const int n = blockIdx.x + 1;
    const int S = T_LEN - n + 1;
    const int s0 = blockIdx.y * 64;
    const int out_off = (n - 1) * (T_LEN + 1) - (n - 1) * n / 2;

    if (tid < 64) {
        int s = s0 + tid; if (s > S - 1) s = S - 1;
        float mx = -1e30f;
        for (int j = 0; j < n; ++j) mx = fmaxf(mx, logits[s + j]);
        float sum = 0.f;
        float ex[10];
        for (int j = 0; j < n; ++j) { ex[j] = expf(logits[s + j] - mx); sum += ex[j]; }
        float inv = 1.f / sum;
        for (int j = 0; j < n; ++j) wbuf[tid][j] = ex[j] * inv;
    }
    __syncthreads();

    // phase 1: 64 rows x 40 float4 (cols 150..159 are zero in U/V/P)
    for (int idx = tid; idx < 64 * 40; idx += 256) {
        int i = idx / 40, p = idx - i * 40;
        int s = s0 + i; if (s > S - 1) s = S - 1;
        float4 pre = ((const float4*)&U[(long)s * 160])[p];
        float4 vv  = ((const float4*)&V[(long)(s + n - 1) * 160])[p];
        pre.x += vv.x; pre.y += vv.y; pre.z += vv.z; pre.w += vv.w;
        for (int j = 0; j < n; ++j) {
            float wj = wbuf[i][j];
            float4 pv = ((const float4*)&Pb[(long)(s + j) * 160])[p];
            pre.x += wj * pv.x; pre.y += wj * pv.y;
            pre.z += wj * pv.z; pre.w += wj * pv.w;
        }
        unsigned lo = pk2(fmaxf(pre.x, 0.f), fmaxf(pre.y, 0.f));
        unsigned hi = pk2(fmaxf(pre.z, 0.f), fmaxf(pre.w, 0.f));
        *(uint2*)&h1s[i * 168 + 4 * p] = make_uint2(lo, hi);
    }
    __syncthreads();

    // phase 2: MFMA, B-frags from global W2t
    const int w = tid >> 6, lane = tid & 63;
    const int ml = lane & 15, kg = lane >> 4;

    bf16x8 af[5];
    #pragma unroll
    for (int ks = 0; ks < 5; ++ks)
        af[ks] = *(const bf16x8*)&h1s[(16 * w + ml) * 168 + ks * 32 + kg * 8];

    float score[4] = {0.f, 0.f, 0.f, 0.f};
    #pragma unroll
    for (int nt = 0; nt < 10; ++nt) {
        f32x4 acc = {0.f, 0.f, 0.f, 0.f};
        #pragma unroll
        for (int ks = 0; ks < 5; ++ks) {
            bf16x8 bf = *(const bf16x8*)&W2t[(long)(nt * 16 + ml) * 168 + ks * 32 + kg * 8];
            acc = __builtin_amdgcn_mfma_f32_16x16x32_bf16(af[ks], bf, acc, 0, 0, 0);
        }
        int col = nt * 16 + ml;
        float b2v = (col < HID) ? b2[col] : 0.f;
        float w3v = (col < HID) ? W3[col] : 0.f;
        #pragma unroll
        for (int r = 0; r < 4; ++r)
            score[r] += fmaxf(acc[r] + b2v, 0.f) * w3v;
    }
    #pragma unroll
    for (int r = 0; r < 4; ++r) {
        score[r] += __shfl_xor(score[r], 1);
        score[r] += __shfl_xor(score[r], 2);
        score[r] += __shfl_xor(score[r], 4);
        score[r] += __shfl_xor(score[r], 8);
    }
    if (ml == 0) {
        float bb = b3[0];
        #pragma unroll
        for (int r = 0; r < 4; ++r) {
            int s = s0 + 16 * w + kg * 4 + r;
            if (s < S) out[out_off + s] = score[r] + bb;
        }
    }
}

// ---------------------------------------------------------------------------
extern "C" void kernel_launch(void* const* d_in, const int* in_sizes, int n_in,
                              void* d_out, int out_size, void* d_ws, size_t ws_size,
                              hipStream_t stream) {
    const float* embeds  = (const float*)d_in[0];
    const float* states  = (const float*)d_in[1];
    const float* attn_W1 = (const float*)d_in[2];
    const float* attn_b1 = (const float*)d_in[3];
    const float* attn_W2 = (const float*)d_in[4];
    const float* attn_b2 = (const float*)d_in[5];
    const float* attn_W3 = (const float*)d_in[6];
    const float* attn_b3 = (const float*)d_in[7];
    const float* sc_W1   = (const float*)d_in[8];
    const float* sc_b1   = (const float*)d_in[9];
    const float* sc_W2   = (const float*)d_in[10];
    const float* sc_b2   = (const float*)d_in[11];
    const float* sc_W3   = (const float*)d_in[12];
    const float* sc_b3   = (const float*)d_in[13];
    float* out = (float*)d_out;

    float* ws = (float*)d_ws;
    float* Ubuf   = ws;                    // [20000][160] = 3.2M floats
    float* Vbuf   = ws + 3200000;          // 3.2M
    float* Pbuf   = ws + 6400000;          // 3.2M
    float* logits = ws + 9600000;          // 20,000
    short* wbf    = (short*)(ws + 9620000); // 318,720 shorts (~0.64 MB); total ~39.1 MB

    wprep<<<1245, 256, 0, stream>>>(sc_W1, attn_W1, attn_W2, sc_W2, wbf);
    big3_mfma<<<dim3(313, 3), 256, 0, stream>>>(states, embeds, wbf, sc_b1,
                                                Ubuf, Vbuf, Pbuf);
    attn_mfma<<<313, 256, 0, stream>>>(states, wbf + 199680, attn_b1,
                                       wbf + 266240, attn_b2, attn_W3, attn_b3,
                                       logits);
    span_mfma<<<dim3(10, 313), 256, 0, stream>>>(Ubuf, Vbuf, Pbuf, logits,
                                                 wbf + 291840, sc_b2, sc_W3, sc_b3,
                                                 out);
}

// Round 5
// 260.441 us; speedup vs baseline: 7.1057x; 1.1469x over previous
//
#include <hip/hip_runtime.h>
#include <hip/hip_bf16.h>
#include <math.h>

#define T_LEN 20000
#define HID 150

typedef __attribute__((ext_vector_type(8))) __bf16 bf16x8;
typedef __attribute__((ext_vector_type(4))) float f32x4;

__device__ __forceinline__ short f2bf(float f) {
    unsigned u = __float_as_uint(f);
    u = (u + 0x7fff + ((u >> 16) & 1)) >> 16;
    return (short)u;
}

__device__ __forceinline__ unsigned pk2(float a, float b) {
    __hip_bfloat162 h = __float22bfloat162_rn(make_float2(a, b));
    return *(unsigned*)&h;
}

__device__ __forceinline__ bf16x8 cvt8(float4 a, float4 b) {
    union { unsigned u[4]; bf16x8 v; } r;
    r.u[0] = pk2(a.x, a.y);
    r.u[1] = pk2(a.z, a.w);
    r.u[2] = pk2(b.x, b.y);
    r.u[3] = pk2(b.z, b.w);
    return r.v;
}

// ---------------------------------------------------------------------------
// wprep: bf16 transposed weights. Layout (shorts):
//   [0,66560)        Bt0 [160][416]  sc_W1 rows   0..399  (U)
//   [66560,133120)   Bt1 [160][416]  sc_W1 rows 400..799  (V)
//   [133120,199680)  At1 [160][416]  attn_W1              (X1)  <- contiguous with Bt0/Bt1
//   [199680,266240)  Bt2 [160][416]  sc_W1 rows 800..1099 (P, K=300)
//   [266240,291840)  At2 [160][160]  attn_W2
//   [291840,318720)  W2t [160][168]  sc_W2
// ---------------------------------------------------------------------------
__global__ __launch_bounds__(256) void wprep(
    const float* __restrict__ sc_W1, const float* __restrict__ attn_W1,
    const float* __restrict__ attn_W2, const float* __restrict__ sc_W2,
    short* __restrict__ wbf)
{
    int t = blockIdx.x * 256 + threadIdx.x;
    if (t >= 318720) return;
    float v = 0.f;
    if (t < 133120) {
        int y = t / 66560, r = t - y * 66560;
        int nn = r / 416, k = r - nn * 416;
        if (nn < HID && k < 400) v = sc_W1[(long)(y * 400 + k) * HID + nn];
    } else if (t < 199680) {
        int r = t - 133120;
        int nn = r / 416, k = r - nn * 416;
        if (nn < HID && k < 400) v = attn_W1[(long)k * HID + nn];
    } else if (t < 266240) {
        int r = t - 199680;
        int nn = r / 416, k = r - nn * 416;
        if (nn < HID && k < 300) v = sc_W1[(long)(800 + k) * HID + nn];
    } else if (t < 291840) {
        int r = t - 266240;
        int nn = r / 160, k = r - nn * 160;
        if (nn < HID && k < HID) v = attn_W2[(long)k * HID + nn];
    } else {
        int r = t - 291840;
        int nn = r / 168, k = r - nn * 168;
        if (nn < HID && k < HID) v = sc_W2[(long)k * HID + nn];
    }
    wbf[t] = f2bf(v);
}

// ---------------------------------------------------------------------------
// fusedA: ONE states pass -> U, V (global fp32, stride 160, pad cols zeroed)
// and X1 = relu(states@attn_W1+b1) (LDS bf16), then attn layers 2+3 -> logits.
// 64 rows/block, 4 waves, 30 output tiles in the K=400 MFMA loop.
// ---------------------------------------------------------------------------
__global__ __launch_bounds__(256) void fusedA(
    const float* __restrict__ states, const short* __restrict__ wbf,
    const float* __restrict__ scb1, const float* __restrict__ ab1,
    const float* __restrict__ ab2, const float* __restrict__ aW3,
    const float* __restrict__ ab3,
    float* __restrict__ U, float* __restrict__ V, float* __restrict__ logits)
{
    __shared__ short h1s[64 * 168];
    const int tid = threadIdx.x;
    const int w = tid >> 6, lane = tid & 63;
    const int ml = lane & 15, kg = lane >> 4;
    const int m0 = blockIdx.x * 64;

    int arow = m0 + 16 * w + ml; if (arow > T_LEN - 1) arow = T_LEN - 1;
    const float* Arow = states + (long)arow * 400;

    f32x4 acc[30];
    #pragma unroll
    for (int nt = 0; nt < 30; ++nt) acc[nt] = (f32x4){0.f, 0.f, 0.f, 0.f};

    for (int ks = 0; ks < 13; ++ks) {
        int k = ks * 32 + kg * 8;
        float4 a0 = make_float4(0.f, 0.f, 0.f, 0.f);
        float4 a1 = make_float4(0.f, 0.f, 0.f, 0.f);
        if (k + 4 <= 400) a0 = *(const float4*)&Arow[k];
        if (k + 8 <= 400) a1 = *(const float4*)&Arow[k + 4];
        bf16x8 af = cvt8(a0, a1);
        #pragma unroll
        for (int nt = 0; nt < 30; ++nt) {
            bf16x8 bf = *(const bf16x8*)&wbf[(long)(nt * 16 + ml) * 416 + k];
            acc[nt] = __builtin_amdgcn_mfma_f32_16x16x32_bf16(af, bf, acc[nt], 0, 0, 0);
        }
    }

    // U (tiles 0..9, +sc_b1) and V (tiles 10..19)
    #pragma unroll
    for (int nt = 0; nt < 10; ++nt) {
        int col = nt * 16 + ml;
        float bv = (col < HID) ? scb1[col] : 0.f;
        #pragma unroll
        for (int r = 0; r < 4; ++r) {
            int gm = m0 + 16 * w + kg * 4 + r;
            if (gm < T_LEN)
                U[(long)gm * 160 + col] = (col < HID) ? acc[nt][r] + bv : 0.f;
        }
    }
    #pragma unroll
    for (int nt = 10; nt < 20; ++nt) {
        int col = (nt - 10) * 16 + ml;
        #pragma unroll
        for (int r = 0; r < 4; ++r) {
            int gm = m0 + 16 * w + kg * 4 + r;
            if (gm < T_LEN)
                V[(long)gm * 160 + col] = (col < HID) ? acc[nt][r] : 0.f;
        }
    }
    // X1 (tiles 20..29) -> relu -> bf16 LDS
    #pragma unroll
    for (int nt = 20; nt < 30; ++nt) {
        int col = (nt - 20) * 16 + ml;
        float bv = (col < HID) ? ab1[col] : 0.f;
        #pragma unroll
        for (int r = 0; r < 4; ++r) {
            int row = kg * 4 + r;
            float v = (col < HID) ? fmaxf(acc[nt][r] + bv, 0.f) : 0.f;
            h1s[(16 * w + row) * 168 + col] = f2bf(v);
        }
    }
    __syncthreads();

    // attn layer 2 (K=160) + relu-dot-W3 epilogue
    const short* At2 = wbf + 266240;
    bf16x8 af2[5];
    #pragma unroll
    for (int ks = 0; ks < 5; ++ks)
        af2[ks] = *(const bf16x8*)&h1s[(16 * w + ml) * 168 + ks * 32 + kg * 8];

    float score[4] = {0.f, 0.f, 0.f, 0.f};
    #pragma unroll
    for (int nt = 0; nt < 10; ++nt) {
        f32x4 a2 = {0.f, 0.f, 0.f, 0.f};
        #pragma unroll
        for (int ks = 0; ks < 5; ++ks) {
            bf16x8 bf = *(const bf16x8*)&At2[(long)(nt * 16 + ml) * 160 + ks * 32 + kg * 8];
            a2 = __builtin_amdgcn_mfma_f32_16x16x32_bf16(af2[ks], bf, a2, 0, 0, 0);
        }
        int col = nt * 16 + ml;
        float b2v = (col < HID) ? ab2[col] : 0.f;
        float w3v = (col < HID) ? aW3[col] : 0.f;
        #pragma unroll
        for (int r = 0; r < 4; ++r)
            score[r] += fmaxf(a2[r] + b2v, 0.f) * w3v;
    }
    #pragma unroll
    for (int r = 0; r < 4; ++r) {
        score[r] += __shfl_xor(score[r], 1);
        score[r] += __shfl_xor(score[r], 2);
        score[r] += __shfl_xor(score[r], 4);
        score[r] += __shfl_xor(score[r], 8);
    }
    if (ml == 0) {
        float bb = ab3[0];
        #pragma unroll
        for (int r = 0; r < 4; ++r) {
            int gm = m0 + 16 * w + kg * 4 + r;
            if (gm < T_LEN) logits[gm] = score[r] + bb;
        }
    }
}

// ---------------------------------------------------------------------------
// pkern: P = embeds @ sc_W1[800:1100] (K=300), stride-160 fp32, pad zeroed.
// ---------------------------------------------------------------------------
__global__ __launch_bounds__(256) void pkern(
    const float* __restrict__ embeds, const short* __restrict__ wbf,
    float* __restrict__ P)
{
    const int tid = threadIdx.x;
    const int w = tid >> 6, lane = tid & 63;
    const int ml = lane & 15, kg = lane >> 4;
    const int m0 = blockIdx.x * 64;
    const short* Bt = wbf + 199680;

    int arow = m0 + 16 * w + ml; if (arow > T_LEN - 1) arow = T_LEN - 1;
    const float* Arow = embeds + (long)arow * 300;

    f32x4 acc[10];
    #pragma unroll
    for (int nt = 0; nt < 10; ++nt) acc[nt] = (f32x4){0.f, 0.f, 0.f, 0.f};

    for (int ks = 0; ks < 10; ++ks) {
        int k = ks * 32 + kg * 8;
        float4 a0 = make_float4(0.f, 0.f, 0.f, 0.f);
        float4 a1 = make_float4(0.f, 0.f, 0.f, 0.f);
        if (k + 4 <= 300) a0 = *(const float4*)&Arow[k];
        if (k + 8 <= 300) a1 = *(const float4*)&Arow[k + 4];
        bf16x8 af = cvt8(a0, a1);
        #pragma unroll
        for (int nt = 0; nt < 10; ++nt) {
            bf16x8 bf = *(const bf16x8*)&Bt[(long)(nt * 16 + ml) * 416 + k];
            acc[nt] = __builtin_amdgcn_mfma_f32_16x16x32_bf16(af, bf, acc[nt], 0, 0, 0);
        }
    }

    #pragma unroll
    for (int nt = 0; nt < 10; ++nt) {
        int col = nt * 16 + ml;
        #pragma unroll
        for (int r = 0; r < 4; ++r) {
            int gm = m0 + 16 * w + kg * 4 + r;
            if (gm < T_LEN)
                P[(long)gm * 160 + col] = (col < HID) ? acc[nt][r] : 0.f;
        }
    }
}

// ---------------------------------------------------------------------------
// span_all: ONE block per 64-span chunk handles ALL widths n=1..10.
// Chunk-max softmax => pooled numerator/denominator incremental in n:
//   acc += e[s+n-1] * P[s+n-1];  den += e;  h1 = relu(U + V[s+n-1] + acc/den)
// Thread (i=tid>>2, q=tid&3) owns span i, dims [40q,40q+40): U + acc in regs,
// each P/V row streamed once (L1-resident). Per n: h1 bf16 -> LDS, then the
// proven 16x16x32 MFMA phase vs W2 (staged once in LDS), relu-dot-W3, store.
// ---------------------------------------------------------------------------
__global__ __launch_bounds__(256) void span_all(
    const float* __restrict__ U, const float* __restrict__ V,
    const float* __restrict__ Pb, const float* __restrict__ logits,
    const short* __restrict__ W2t, const float* __restrict__ b2,
    const float* __restrict__ W3, const float* __restrict__ b3,
    float* __restrict__ out)
{
    __shared__ short W2s[160 * 168];   // 53760 B
    __shared__ short h1s[64 * 168];    // 21504 B
    __shared__ float Ls[73];
    __shared__ float ebuf[73];

    const int tid = threadIdx.x;
    const int s0 = blockIdx.x * 64;

    // stage W2 (bf16, padded) once
    {
        const float4* wg = (const float4*)W2t;
        float4* wl = (float4*)W2s;
        for (int t = tid; t < 3360; t += 256) wl[t] = wg[t];
    }
    if (tid < 73) {
        int r = s0 + tid; if (r > T_LEN - 1) r = T_LEN - 1;
        Ls[tid] = logits[r];
    }
    __syncthreads();
    if (tid < 73) {
        float M = -1e30f;
        for (int t = 0; t < 73; ++t) M = fmaxf(M, Ls[t]);
        ebuf[tid] = expf(Ls[tid] - M);
    }
    __syncthreads();

    const int i = tid >> 2;       // span within chunk
    const int q = tid & 3;        // dim quarter: [40q, 40q+40)
    const int s = s0 + i;
    int su = s; if (su > T_LEN - 1) su = T_LEN - 1;

    float4 Ur[10];
    {
        const float4* U4 = (const float4*)(U + (long)su * 160) + q * 10;
        #pragma unroll
        for (int p = 0; p < 10; ++p) Ur[p] = U4[p];
    }
    float accp[40];
    #pragma unroll
    for (int d = 0; d < 40; ++d) accp[d] = 0.f;
    float den = 0.f;

    const int w = tid >> 6, lane = tid & 63;
    const int ml = lane & 15, kg = lane >> 4;

    for (int n = 1; n <= 10; ++n) {
        // --- phase 1: incremental pooled + h1 -> bf16 LDS
        int r = s + n - 1; if (r > T_LEN - 1) r = T_LEN - 1;
        float e = ebuf[i + n - 1];
        den += e;
        {
            const float4* Pr = (const float4*)(Pb + (long)r * 160) + q * 10;
            #pragma unroll
            for (int p = 0; p < 10; ++p) {
                float4 pv = Pr[p];
                accp[4 * p + 0] += e * pv.x;
                accp[4 * p + 1] += e * pv.y;
                accp[4 * p + 2] += e * pv.z;
                accp[4 * p + 3] += e * pv.w;
            }
        }
        float invd = 1.f / den;
        {
            const float4* Vr = (const float4*)(V + (long)r * 160) + q * 10;
            #pragma unroll
            for (int p = 0; p < 10; ++p) {
                float4 vv = Vr[p];
                float x0 = fmaxf(Ur[p].x + vv.x + accp[4 * p + 0] * invd, 0.f);
                float x1 = fmaxf(Ur[p].y + vv.y + accp[4 * p + 1] * invd, 0.f);
                float x2 = fmaxf(Ur[p].z + vv.z + accp[4 * p + 2] * invd, 0.f);
                float x3 = fmaxf(Ur[p].w + vv.w + accp[4 * p + 3] * invd, 0.f);
                *(uint2*)&h1s[i * 168 + 40 * q + 4 * p] =
                    make_uint2(pk2(x0, x1), pk2(x2, x3));
            }
        }
        __syncthreads();

        // --- phase 2: MFMA h1 @ W2, epilogue relu-dot-W3
        bf16x8 af[5];
        #pragma unroll
        for (int ks = 0; ks < 5; ++ks)
            af[ks] = *(const bf16x8*)&h1s[(16 * w + ml) * 168 + ks * 32 + kg * 8];

        float score[4] = {0.f, 0.f, 0.f, 0.f};
        #pragma unroll
        for (int nt = 0; nt < 10; ++nt) {
            f32x4 am = {0.f, 0.f, 0.f, 0.f};
            #pragma unroll
            for (int ks = 0; ks < 5; ++ks) {
                bf16x8 bf = *(const bf16x8*)&W2s[(nt * 16 + ml) * 168 + ks * 32 + kg * 8];
                am = __builtin_amdgcn_mfma_f32_16x16x32_bf16(af[ks], bf, am, 0, 0, 0);
            }
            int col = nt * 16 + ml;
            float b2v = (col < HID) ? b2[col] : 0.f;
            float w3v = (col < HID) ? W3[col] : 0.f;
            #pragma unroll
            for (int rr = 0; rr < 4; ++rr)
                score[rr] += fmaxf(am[rr] + b2v, 0.f) * w3v;
        }
        #pragma unroll
        for (int rr = 0; rr < 4; ++rr) {
            score[rr] += __shfl_xor(score[rr], 1);
            score[rr] += __shfl_xor(score[rr], 2);
            score[rr] += __shfl_xor(score[rr], 4);
            score[rr] += __shfl_xor(score[rr], 8);
        }
        if (ml == 0) {
            const int S = T_LEN - n + 1;
            const int out_off = (n - 1) * (T_LEN + 1) - (n - 1) * n / 2;
            float bb = b3[0];
            #pragma unroll
            for (int rr = 0; rr < 4; ++rr) {
                int sr = s0 + 16 * w + kg * 4 + rr;
                if (sr < S) out[out_off + sr] = score[rr] + bb;
            }
        }
        __syncthreads();   // before next n overwrites h1s
    }
}

// ---------------------------------------------------------------------------
extern "C" void kernel_launch(void* const* d_in, const int* in_sizes, int n_in,
                              void* d_out, int out_size, void* d_ws, size_t ws_size,
                              hipStream_t stream) {
    const float* embeds  = (const float*)d_in[0];
    const float* states  = (const float*)d_in[1];
    const float* attn_W1 = (const float*)d_in[2];
    const float* attn_b1 = (const float*)d_in[3];
    const float* attn_W2 = (const float*)d_in[4];
    const float* attn_b2 = (const float*)d_in[5];
    const float* attn_W3 = (const float*)d_in[6];
    const float* attn_b3 = (const float*)d_in[7];
    const float* sc_W1   = (const float*)d_in[8];
    const float* sc_b1   = (const float*)d_in[9];
    const float* sc_W2   = (const float*)d_in[10];
    const float* sc_b2   = (const float*)d_in[11];
    const float* sc_W3   = (const float*)d_in[12];
    const float* sc_b3   = (const float*)d_in[13];
    float* out = (float*)d_out;

    float* ws = (float*)d_ws;
    float* Ubuf   = ws;                     // [20000][160] fp32
    float* Vbuf   = ws + 3200000;
    float* Pbuf   = ws + 6400000;
    float* logits = ws + 9600000;           // 20,000
    short* wbf    = (short*)(ws + 9620000); // 318,720 shorts

    wprep<<<1245, 256, 0, stream>>>(sc_W1, attn_W1, attn_W2, sc_W2, wbf);
    fusedA<<<313, 256, 0, stream>>>(states, wbf, sc_b1, attn_b1,
                                    attn_b2, attn_W3, attn_b3,
                                    Ubuf, Vbuf, logits);
    pkern<<<313, 256, 0, stream>>>(embeds, wbf, Pbuf);
    span_all<<<313, 256, 0, stream>>>(Ubuf, Vbuf, Pbuf, logits,
                                      wbf + 291840, sc_b2, sc_W3, sc_b3,
                                      out);
}